// Round 2
// baseline (631.240 us; speedup 1.0000x reference)
//
#include <hip/hip_runtime.h>
#include <stdint.h>

// ---------------------------------------------------------------------------
// MLP_Model: candidates head + per-route Customer MLP + 2-layer GRU + FC head
// R2: GRU restructured into two phases with REGISTER-RESIDENT weights.
//   Phase A (layer0): wih0+whh0 in VGPRs (120), h0(t) streamed to ws (bf16).
//   Phase B (layer1): whh1 in VGPRs (96), wih1 streamed from L2, h0 read back.
// 1 barrier/step (was 2), no per-step L2 weight reload for layer0.
// Fallback to R1 fused kernel if ws_size < ~202 MB.
// ---------------------------------------------------------------------------

#define NSEQ   24576   // 512 * 48
#define TSTEPS 24

typedef __attribute__((ext_vector_type(8))) short bf16x8;
typedef __attribute__((ext_vector_type(4))) float floatx4;

// packed-weight element offsets (uint16 units)
#define PK_W1    0
#define PK_W2    8192
#define PK_WIH0  12288
#define PK_WHH0  24576
#define PK_WIH1  73728
#define PK_WHH1  122880
#define PK_END   172032
#define X2_EL    172032                         // x2: [t][seq][32] bf16
#define H0_EL    (X2_EL + NSEQ * TSTEPS * 32)   // h0_all: [t][seq][128] bf16
#define HOUT_NEW_BYTE ((size_t)(H0_EL + (size_t)NSEQ * TSTEPS * 128) * 2)
#define WS_NEED_NEW   (HOUT_NEW_BYTE + (size_t)NSEQ * 128 * 4)
#define HOUT_OLD_BYTE 38092800

#define MFMA(a,b,c) c = __builtin_amdgcn_mfma_f32_16x16x32_bf16(a, b, c, 0, 0, 0)

__device__ __forceinline__ uint16_t f2bf(float f) {
  uint32_t u = __float_as_uint(f);
  u += 0x7FFFu + ((u >> 16) & 1u);           // RNE
  return (uint16_t)(u >> 16);
}
__device__ __forceinline__ float fast_sigmoid(float x) {
  float e = __builtin_amdgcn_exp2f(-1.4426950408889634f * x);
  return __builtin_amdgcn_rcpf(1.0f + e);
}
__device__ __forceinline__ float fast_tanh(float x) {
  float e = __builtin_amdgcn_exp2f(-2.8853900817779268f * x);
  return 2.0f * __builtin_amdgcn_rcpf(1.0f + e) - 1.0f;
}
__device__ __forceinline__ bf16x8 ldf(const uint16_t* p) {
  return *(const bf16x8*)p;
}

// ---------------------------------------------------------------------------
// Kernel 0: pack all weights to bf16 B-fragment layout. (unchanged from R1)
// ---------------------------------------------------------------------------
__global__ __launch_bounds__(256) void pack_weights(
    const float* __restrict__ w1, const float* __restrict__ w2,
    const float* __restrict__ wih0, const float* __restrict__ whh0,
    const float* __restrict__ wih1, const float* __restrict__ whh1,
    uint16_t* __restrict__ ws) {
  int idx = blockIdx.x * 256 + threadIdx.x;
  if (idx >= PK_END) return;
  const float* W; int N, KB, Kreal, base;
  if      (idx <  8192) { W = w1;   N = 128; KB = 2; Kreal = 36;  base = 0; }
  else if (idx < 12288) { W = w2;   N = 32;  KB = 4; Kreal = 128; base = 8192; }
  else if (idx < 24576) { W = wih0; N = 384; KB = 1; Kreal = 32;  base = 12288; }
  else if (idx < 73728) { W = whh0; N = 384; KB = 4; Kreal = 128; base = 24576; }
  else if (idx < 122880){ W = wih1; N = 384; KB = 4; Kreal = 128; base = 73728; }
  else                  { W = whh1; N = 384; KB = 4; Kreal = 128; base = 122880; }
  int li = idx - base;
  int frag = li >> 9;
  int e = li & 511;
  int lane = e >> 3, j = e & 7;
  int kb = frag % KB, nt = frag / KB;
  int k = kb * 32 + (lane >> 4) * 8 + j;
  int n = nt * 16 + (lane & 15);
  float v = (k < Kreal) ? W[k * N + n] : 0.0f;
  ws[base + li] = f2bf(v);
}

// ---------------------------------------------------------------------------
// Kernel 1: Customer MLP (unchanged from R1)
// ---------------------------------------------------------------------------
__global__ __launch_bounds__(256) void mlp_kernel(
    const float* __restrict__ customers, const float* __restrict__ b1,
    const float* __restrict__ b2, const uint16_t* __restrict__ wpk,
    uint16_t* __restrict__ x2out) {
  __shared__ uint16_t sA[128 * 136];
  const int r0 = blockIdx.x * 128;
  const int t  = r0 / NSEQ;
  const int s0 = r0 % NSEQ;
  const int tid = threadIdx.x;
  const int w = tid >> 6, l = tid & 63, q = l >> 4, c = l & 15;
  const int lo8 = l * 8;

  float b1r[8], b2r[2];
  #pragma unroll
  for (int nt = 0; nt < 8; ++nt) b1r[nt] = b1[nt * 16 + c];
  b2r[0] = b2[c]; b2r[1] = b2[16 + c];

  floatx4 acc[2][8];
  #pragma unroll
  for (int mi = 0; mi < 2; ++mi)
    #pragma unroll
    for (int nt = 0; nt < 8; ++nt) acc[mi][nt] = (floatx4){0.f, 0.f, 0.f, 0.f};

  #pragma unroll
  for (int mi = 0; mi < 2; ++mi) {
    const int mt = 2 * w + mi;
    const int seq = s0 + mt * 16 + c;
    const float* xp = customers + (size_t)seq * 864 + t * 36;
    floatx4 u0 = *(const floatx4*)(xp + q * 8);
    floatx4 u1 = *(const floatx4*)(xp + q * 8 + 4);
    bf16x8 a0;
    a0[0] = (short)f2bf(u0[0]); a0[1] = (short)f2bf(u0[1]);
    a0[2] = (short)f2bf(u0[2]); a0[3] = (short)f2bf(u0[3]);
    a0[4] = (short)f2bf(u1[0]); a0[5] = (short)f2bf(u1[1]);
    a0[6] = (short)f2bf(u1[2]); a0[7] = (short)f2bf(u1[3]);
    bf16x8 a1x = (bf16x8){0,0,0,0,0,0,0,0};
    if (q == 0) {
      floatx4 u2 = *(const floatx4*)(xp + 32);
      a1x[0] = (short)f2bf(u2[0]); a1x[1] = (short)f2bf(u2[1]);
      a1x[2] = (short)f2bf(u2[2]); a1x[3] = (short)f2bf(u2[3]);
    }
    #pragma unroll
    for (int nt = 0; nt < 8; ++nt) {
      bf16x8 bv0 = ldf(wpk + PK_W1 + (nt * 2 + 0) * 512 + lo8);
      bf16x8 bv1 = ldf(wpk + PK_W1 + (nt * 2 + 1) * 512 + lo8);
      MFMA(a0,  bv0, acc[mi][nt]);
      MFMA(a1x, bv1, acc[mi][nt]);
    }
  }
  #pragma unroll
  for (int mi = 0; mi < 2; ++mi) {
    const int mt = 2 * w + mi;
    #pragma unroll
    for (int nt = 0; nt < 8; ++nt)
      #pragma unroll
      for (int e = 0; e < 4; ++e) {
        float v = fast_tanh(acc[mi][nt][e] + b1r[nt]);
        sA[(mt * 16 + q * 4 + e) * 136 + nt * 16 + c] = f2bf(v);
      }
  }
  __syncthreads();

  floatx4 acc2[2][2];
  #pragma unroll
  for (int mi = 0; mi < 2; ++mi)
    #pragma unroll
    for (int nt = 0; nt < 2; ++nt) acc2[mi][nt] = (floatx4){0.f, 0.f, 0.f, 0.f};

  #pragma unroll
  for (int kb = 0; kb < 4; ++kb) {
    bf16x8 av0 = ldf(&sA[((2 * w + 0) * 16 + c) * 136 + kb * 32 + q * 8]);
    bf16x8 av1 = ldf(&sA[((2 * w + 1) * 16 + c) * 136 + kb * 32 + q * 8]);
    #pragma unroll
    for (int nt = 0; nt < 2; ++nt) {
      bf16x8 bv = ldf(wpk + PK_W2 + (nt * 4 + kb) * 512 + lo8);
      MFMA(av0, bv, acc2[0][nt]);
      MFMA(av1, bv, acc2[1][nt]);
    }
  }
  #pragma unroll
  for (int mi = 0; mi < 2; ++mi) {
    const int mt = 2 * w + mi;
    #pragma unroll
    for (int nt = 0; nt < 2; ++nt)
      #pragma unroll
      for (int e = 0; e < 4; ++e) {
        float v = fast_tanh(acc2[mi][nt][e] + b2r[nt]);
        int m = mt * 16 + q * 4 + e;
        x2out[(size_t)(r0 + m) * 32 + nt * 16 + c] = f2bf(v);
      }
  }
}

// ---------------------------------------------------------------------------
// Kernel 2 (NEW): two-phase GRU, weights register-resident.
// 256 thr = 4 waves, wave owns J-tiles {2w, 2w+1}, 32 seqs/block, grid 768.
// ---------------------------------------------------------------------------
__global__ __launch_bounds__(256, 2) void gru_split(
    const uint16_t* __restrict__ wpk, const uint16_t* __restrict__ x2,
    uint16_t* __restrict__ h0g,
    const float* __restrict__ bih0, const float* __restrict__ bhh0,
    const float* __restrict__ bih1, const float* __restrict__ bhh1,
    float* __restrict__ hout) {
  __shared__ uint16_t hl[2][32 * 136];
  const int seq0 = blockIdx.x * 32;
  const int tid = threadIdx.x;
  const int w = tid >> 6, l = tid & 63, q = l >> 4, c = l & 15;
  const int lo8 = l * 8;

  { uint32_t* z = (uint32_t*)hl;
    for (int i = tid; i < 2 * 32 * 68; i += 256) z[i] = 0u; }
  __syncthreads();

  floatx4 hm[2][2];

  // ======================= phase A : GRU layer 0 =======================
  {
    bf16x8 wih[2][3], whh[2][3][4];
    float bR[2], bZ[2], bN[2], bH[2];
    #pragma unroll
    for (int ji = 0; ji < 2; ++ji) {
      const int J = 2 * w + ji;
      #pragma unroll
      for (int g = 0; g < 3; ++g) {
        wih[ji][g] = ldf(wpk + PK_WIH0 + (g * 8 + J) * 512 + lo8);
        #pragma unroll
        for (int kb = 0; kb < 4; ++kb)
          whh[ji][g][kb] = ldf(wpk + PK_WHH0 + ((g * 8 + J) * 4 + kb) * 512 + lo8);
      }
      const int col = J * 16 + c;
      bR[ji] = bih0[col]       + bhh0[col];
      bZ[ji] = bih0[128 + col] + bhh0[128 + col];
      bN[ji] = bih0[256 + col];
      bH[ji] = bhh0[256 + col];
      hm[ji][0] = (floatx4){0.f, 0.f, 0.f, 0.f};
      hm[ji][1] = (floatx4){0.f, 0.f, 0.f, 0.f};
    }

    bf16x8 ax0 = ldf(x2 + (size_t)(seq0 + c) * 32 + q * 8);
    bf16x8 ax1 = ldf(x2 + (size_t)(seq0 + 16 + c) * 32 + q * 8);

    for (int t = 0; t < TSTEPS; ++t) {
      const int cur = t & 1, prv = cur ^ 1;
      const int tn = (t < TSTEPS - 1) ? t + 1 : t;
      bf16x8 axn0 = ldf(x2 + ((size_t)tn * NSEQ + seq0 + c) * 32 + q * 8);
      bf16x8 axn1 = ldf(x2 + ((size_t)tn * NSEQ + seq0 + 16 + c) * 32 + q * 8);

      floatx4 aR[2][2], aZ[2][2], aN[2][2], aH[2][2];
      #pragma unroll
      for (int ji = 0; ji < 2; ++ji)
        #pragma unroll
        for (int mi = 0; mi < 2; ++mi) {
          aR[ji][mi] = (floatx4){bR[ji], bR[ji], bR[ji], bR[ji]};
          aZ[ji][mi] = (floatx4){bZ[ji], bZ[ji], bZ[ji], bZ[ji]};
          aN[ji][mi] = (floatx4){bN[ji], bN[ji], bN[ji], bN[ji]};
          aH[ji][mi] = (floatx4){bH[ji], bH[ji], bH[ji], bH[ji]};
        }
      #pragma unroll
      for (int kb = 0; kb < 4; ++kb) {
        bf16x8 h0v = ldf(&hl[prv][(c)      * 136 + kb * 32 + q * 8]);
        bf16x8 h1v = ldf(&hl[prv][(16 + c) * 136 + kb * 32 + q * 8]);
        #pragma unroll
        for (int ji = 0; ji < 2; ++ji) {
          MFMA(h0v, whh[ji][0][kb], aR[ji][0]); MFMA(h1v, whh[ji][0][kb], aR[ji][1]);
          MFMA(h0v, whh[ji][1][kb], aZ[ji][0]); MFMA(h1v, whh[ji][1][kb], aZ[ji][1]);
          MFMA(h0v, whh[ji][2][kb], aH[ji][0]); MFMA(h1v, whh[ji][2][kb], aH[ji][1]);
        }
      }
      #pragma unroll
      for (int ji = 0; ji < 2; ++ji) {
        MFMA(ax0, wih[ji][0], aR[ji][0]); MFMA(ax1, wih[ji][0], aR[ji][1]);
        MFMA(ax0, wih[ji][1], aZ[ji][0]); MFMA(ax1, wih[ji][1], aZ[ji][1]);
        MFMA(ax0, wih[ji][2], aN[ji][0]); MFMA(ax1, wih[ji][2], aN[ji][1]);
      }
      #pragma unroll
      for (int ji = 0; ji < 2; ++ji) {
        const int J = 2 * w + ji;
        #pragma unroll
        for (int mi = 0; mi < 2; ++mi)
          #pragma unroll
          for (int e = 0; e < 4; ++e) {
            float r  = fast_sigmoid(aR[ji][mi][e]);
            float zz = fast_sigmoid(aZ[ji][mi][e]);
            float nn = fast_tanh(aN[ji][mi][e] + r * aH[ji][mi][e]);
            float hv = nn + zz * (hm[ji][mi][e] - nn);
            hm[ji][mi][e] = hv;
            hl[cur][(mi * 16 + q * 4 + e) * 136 + J * 16 + c] = f2bf(hv);
          }
      }
      __syncthreads();
      // coalesced copy h0(t) -> global (row-major [t][seq][128])
      {
        const int row = tid >> 3, ch = tid & 7;
        uint16_t* dst = h0g + (size_t)t * NSEQ * 128 + (size_t)(seq0 + row) * 128;
        *(bf16x8*)(dst + ch * 8)      = *(const bf16x8*)&hl[cur][row * 136 + ch * 8];
        *(bf16x8*)(dst + 64 + ch * 8) = *(const bf16x8*)&hl[cur][row * 136 + 64 + ch * 8];
      }
      ax0 = axn0; ax1 = axn1;
    }
  }
  __syncthreads();
  { uint32_t* z = (uint32_t*)hl;
    for (int i = tid; i < 2 * 32 * 68; i += 256) z[i] = 0u; }
  __syncthreads();

  // ======================= phase B : GRU layer 1 =======================
  {
    bf16x8 whh[2][3][4];
    float bR[2], bZ[2], bN[2], bH[2];
    #pragma unroll
    for (int ji = 0; ji < 2; ++ji) {
      const int J = 2 * w + ji;
      #pragma unroll
      for (int g = 0; g < 3; ++g)
        #pragma unroll
        for (int kb = 0; kb < 4; ++kb)
          whh[ji][g][kb] = ldf(wpk + PK_WHH1 + ((g * 8 + J) * 4 + kb) * 512 + lo8);
      const int col = J * 16 + c;
      bR[ji] = bih1[col]       + bhh1[col];
      bZ[ji] = bih1[128 + col] + bhh1[128 + col];
      bN[ji] = bih1[256 + col];
      bH[ji] = bhh1[256 + col];
      hm[ji][0] = (floatx4){0.f, 0.f, 0.f, 0.f};
      hm[ji][1] = (floatx4){0.f, 0.f, 0.f, 0.f};
    }

    for (int t = 0; t < TSTEPS; ++t) {
      const int cur = t & 1, prv = cur ^ 1;
      // x1(t) = h0(t) A-fragments from global
      bf16x8 xa[4][2];
      #pragma unroll
      for (int kb = 0; kb < 4; ++kb) {
        xa[kb][0] = ldf(h0g + ((size_t)t * NSEQ + seq0 + c)      * 128 + kb * 32 + q * 8);
        xa[kb][1] = ldf(h0g + ((size_t)t * NSEQ + seq0 + 16 + c) * 128 + kb * 32 + q * 8);
      }
      floatx4 aR[2][2], aZ[2][2], aN[2][2], aH[2][2];
      #pragma unroll
      for (int ji = 0; ji < 2; ++ji)
        #pragma unroll
        for (int mi = 0; mi < 2; ++mi) {
          aR[ji][mi] = (floatx4){bR[ji], bR[ji], bR[ji], bR[ji]};
          aZ[ji][mi] = (floatx4){bZ[ji], bZ[ji], bZ[ji], bZ[ji]};
          aN[ji][mi] = (floatx4){bN[ji], bN[ji], bN[ji], bN[ji]};
          aH[ji][mi] = (floatx4){bH[ji], bH[ji], bH[ji], bH[ji]};
        }
      // gi = x1 @ wih1 (weights streamed from L2)
      #pragma unroll
      for (int kb = 0; kb < 4; ++kb) {
        #pragma unroll
        for (int ji = 0; ji < 2; ++ji) {
          const int J = 2 * w + ji;
          bf16x8 wr = ldf(wpk + PK_WIH1 + ((0 * 8 + J) * 4 + kb) * 512 + lo8);
          bf16x8 wz = ldf(wpk + PK_WIH1 + ((1 * 8 + J) * 4 + kb) * 512 + lo8);
          bf16x8 wn = ldf(wpk + PK_WIH1 + ((2 * 8 + J) * 4 + kb) * 512 + lo8);
          MFMA(xa[kb][0], wr, aR[ji][0]); MFMA(xa[kb][1], wr, aR[ji][1]);
          MFMA(xa[kb][0], wz, aZ[ji][0]); MFMA(xa[kb][1], wz, aZ[ji][1]);
          MFMA(xa[kb][0], wn, aN[ji][0]); MFMA(xa[kb][1], wn, aN[ji][1]);
        }
      }
      // gh = h1(t-1) @ whh1 (weights resident, A from LDS)
      #pragma unroll
      for (int kb = 0; kb < 4; ++kb) {
        bf16x8 h0v = ldf(&hl[prv][(c)      * 136 + kb * 32 + q * 8]);
        bf16x8 h1v = ldf(&hl[prv][(16 + c) * 136 + kb * 32 + q * 8]);
        #pragma unroll
        for (int ji = 0; ji < 2; ++ji) {
          MFMA(h0v, whh[ji][0][kb], aR[ji][0]); MFMA(h1v, whh[ji][0][kb], aR[ji][1]);
          MFMA(h0v, whh[ji][1][kb], aZ[ji][0]); MFMA(h1v, whh[ji][1][kb], aZ[ji][1]);
          MFMA(h0v, whh[ji][2][kb], aH[ji][0]); MFMA(h1v, whh[ji][2][kb], aH[ji][1]);
        }
      }
      #pragma unroll
      for (int ji = 0; ji < 2; ++ji) {
        const int J = 2 * w + ji;
        #pragma unroll
        for (int mi = 0; mi < 2; ++mi)
          #pragma unroll
          for (int e = 0; e < 4; ++e) {
            float r  = fast_sigmoid(aR[ji][mi][e]);
            float zz = fast_sigmoid(aZ[ji][mi][e]);
            float nn = fast_tanh(aN[ji][mi][e] + r * aH[ji][mi][e]);
            float hv = nn + zz * (hm[ji][mi][e] - nn);
            hm[ji][mi][e] = hv;
            hl[cur][(mi * 16 + q * 4 + e) * 136 + J * 16 + c] = f2bf(hv);
          }
      }
      __syncthreads();
    }
    #pragma unroll
    for (int ji = 0; ji < 2; ++ji) {
      const int J = 2 * w + ji;
      #pragma unroll
      for (int mi = 0; mi < 2; ++mi)
        #pragma unroll
        for (int e = 0; e < 4; ++e) {
          int seq = seq0 + mi * 16 + q * 4 + e;
          hout[(size_t)seq * 128 + J * 16 + c] = hm[ji][mi][e];
        }
    }
  }
}

// ---------------------------------------------------------------------------
// Kernel 2 (FALLBACK, R1): fused 2-layer GRU, used when ws_size is small.
// ---------------------------------------------------------------------------
__global__ __launch_bounds__(256) void gru_fused(
    const uint16_t* __restrict__ wpk, const uint16_t* __restrict__ x2,
    const float* __restrict__ bih0, const float* __restrict__ bhh0,
    const float* __restrict__ bih1, const float* __restrict__ bhh1,
    float* __restrict__ hout) {
  __shared__ uint16_t hl[2][2][32 * 136];
  const int seq0 = blockIdx.x * 32;
  const int tid = threadIdx.x;
  const int w = tid >> 6, l = tid & 63, q = l >> 4, c = l & 15;
  const int lo8 = l * 8;

  { uint32_t* z = (uint32_t*)hl;
    for (int i = tid; i < 8704; i += 256) z[i] = 0u; }
  __syncthreads();

  floatx4 h0m[2][2], h1m[2][2];
  #pragma unroll
  for (int ji = 0; ji < 2; ++ji)
    #pragma unroll
    for (int mi = 0; mi < 2; ++mi) {
      h0m[ji][mi] = (floatx4){0.f, 0.f, 0.f, 0.f};
      h1m[ji][mi] = (floatx4){0.f, 0.f, 0.f, 0.f};
    }

  float bi0[2][3], bh0[2][3], bi1[2][3], bh1[2][3];
  #pragma unroll
  for (int ji = 0; ji < 2; ++ji) {
    int J = 2 * w + ji;
    #pragma unroll
    for (int g = 0; g < 3; ++g) {
      int col = g * 128 + J * 16 + c;
      bi0[ji][g] = bih0[col]; bh0[ji][g] = bhh0[col];
      bi1[ji][g] = bih1[col]; bh1[ji][g] = bhh1[col];
    }
  }

  bf16x8 axc[2], axn[2];
  #pragma unroll
  for (int mi = 0; mi < 2; ++mi)
    axc[mi] = ldf(x2 + (size_t)(seq0 + mi * 16 + c) * 32 + q * 8);

  for (int t = 0; t < TSTEPS; ++t) {
    const int cur = t & 1, prv = cur ^ 1;
    const int tn = (t < TSTEPS - 1) ? t + 1 : t;
    #pragma unroll
    for (int mi = 0; mi < 2; ++mi)
      axn[mi] = ldf(x2 + (size_t)(tn * NSEQ + seq0 + mi * 16 + c) * 32 + q * 8);

    uint16_t* h0w = hl[0][cur]; const uint16_t* h0r = hl[0][prv];
    uint16_t* h1w = hl[1][cur]; const uint16_t* h1r = hl[1][prv];

    #pragma unroll
    for (int ji = 0; ji < 2; ++ji) {
      const int J = 2 * w + ji;
      floatx4 gr[2], gz[2], gn[2], hr[2], hz[2], hn[2];
      #pragma unroll
      for (int mi = 0; mi < 2; ++mi) {
        gr[mi] = (floatx4){bi0[ji][0], bi0[ji][0], bi0[ji][0], bi0[ji][0]};
        gz[mi] = (floatx4){bi0[ji][1], bi0[ji][1], bi0[ji][1], bi0[ji][1]};
        gn[mi] = (floatx4){bi0[ji][2], bi0[ji][2], bi0[ji][2], bi0[ji][2]};
        hr[mi] = (floatx4){bh0[ji][0], bh0[ji][0], bh0[ji][0], bh0[ji][0]};
        hz[mi] = (floatx4){bh0[ji][1], bh0[ji][1], bh0[ji][1], bh0[ji][1]};
        hn[mi] = (floatx4){bh0[ji][2], bh0[ji][2], bh0[ji][2], bh0[ji][2]};
      }
      #pragma unroll
      for (int kb = 0; kb < 4; ++kb) {
        bf16x8 a0  = ldf(h0r + (c) * 136 + kb * 32 + q * 8);
        bf16x8 a1v = ldf(h0r + (16 + c) * 136 + kb * 32 + q * 8);
        bf16x8 brv = ldf(wpk + PK_WHH0 + ((J) * 4 + kb) * 512 + lo8);
        bf16x8 bzv = ldf(wpk + PK_WHH0 + ((8 + J) * 4 + kb) * 512 + lo8);
        bf16x8 bnv = ldf(wpk + PK_WHH0 + ((16 + J) * 4 + kb) * 512 + lo8);
        MFMA(a0, brv, hr[0]); MFMA(a1v, brv, hr[1]);
        MFMA(a0, bzv, hz[0]); MFMA(a1v, bzv, hz[1]);
        MFMA(a0, bnv, hn[0]); MFMA(a1v, bnv, hn[1]);
      }
      {
        bf16x8 brv = ldf(wpk + PK_WIH0 + (J) * 512 + lo8);
        bf16x8 bzv = ldf(wpk + PK_WIH0 + (8 + J) * 512 + lo8);
        bf16x8 bnv = ldf(wpk + PK_WIH0 + (16 + J) * 512 + lo8);
        MFMA(axc[0], brv, gr[0]); MFMA(axc[1], brv, gr[1]);
        MFMA(axc[0], bzv, gz[0]); MFMA(axc[1], bzv, gz[1]);
        MFMA(axc[0], bnv, gn[0]); MFMA(axc[1], bnv, gn[1]);
      }
      #pragma unroll
      for (int mi = 0; mi < 2; ++mi)
        #pragma unroll
        for (int e = 0; e < 4; ++e) {
          float r  = fast_sigmoid(gr[mi][e] + hr[mi][e]);
          float zz = fast_sigmoid(gz[mi][e] + hz[mi][e]);
          float nn = fast_tanh(gn[mi][e] + r * hn[mi][e]);
          float ho = h0m[ji][mi][e];
          float hv = nn + zz * (ho - nn);
          h0m[ji][mi][e] = hv;
          h0w[(mi * 16 + q * 4 + e) * 136 + J * 16 + c] = f2bf(hv);
        }
    }
    __syncthreads();

    #pragma unroll
    for (int ji = 0; ji < 2; ++ji) {
      const int J = 2 * w + ji;
      floatx4 gr[2], gz[2], gn[2], hr[2], hz[2], hn[2];
      #pragma unroll
      for (int mi = 0; mi < 2; ++mi) {
        gr[mi] = (floatx4){bi1[ji][0], bi1[ji][0], bi1[ji][0], bi1[ji][0]};
        gz[mi] = (floatx4){bi1[ji][1], bi1[ji][1], bi1[ji][1], bi1[ji][1]};
        gn[mi] = (floatx4){bi1[ji][2], bi1[ji][2], bi1[ji][2], bi1[ji][2]};
        hr[mi] = (floatx4){bh1[ji][0], bh1[ji][0], bh1[ji][0], bh1[ji][0]};
        hz[mi] = (floatx4){bh1[ji][1], bh1[ji][1], bh1[ji][1], bh1[ji][1]};
        hn[mi] = (floatx4){bh1[ji][2], bh1[ji][2], bh1[ji][2], bh1[ji][2]};
      }
      #pragma unroll
      for (int kb = 0; kb < 4; ++kb) {
        bf16x8 ai0 = ldf(h0w + (c) * 136 + kb * 32 + q * 8);
        bf16x8 ai1 = ldf(h0w + (16 + c) * 136 + kb * 32 + q * 8);
        bf16x8 ah0 = ldf(h1r + (c) * 136 + kb * 32 + q * 8);
        bf16x8 ah1 = ldf(h1r + (16 + c) * 136 + kb * 32 + q * 8);
        bf16x8 birv = ldf(wpk + PK_WIH1 + ((J) * 4 + kb) * 512 + lo8);
        bf16x8 bizv = ldf(wpk + PK_WIH1 + ((8 + J) * 4 + kb) * 512 + lo8);
        bf16x8 binv = ldf(wpk + PK_WIH1 + ((16 + J) * 4 + kb) * 512 + lo8);
        bf16x8 bhrv = ldf(wpk + PK_WHH1 + ((J) * 4 + kb) * 512 + lo8);
        bf16x8 bhzv = ldf(wpk + PK_WHH1 + ((8 + J) * 4 + kb) * 512 + lo8);
        bf16x8 bhnv = ldf(wpk + PK_WHH1 + ((16 + J) * 4 + kb) * 512 + lo8);
        MFMA(ai0, birv, gr[0]); MFMA(ai1, birv, gr[1]);
        MFMA(ai0, bizv, gz[0]); MFMA(ai1, bizv, gz[1]);
        MFMA(ai0, binv, gn[0]); MFMA(ai1, binv, gn[1]);
        MFMA(ah0, bhrv, hr[0]); MFMA(ah1, bhrv, hr[1]);
        MFMA(ah0, bhzv, hz[0]); MFMA(ah1, bhzv, hz[1]);
        MFMA(ah0, bhnv, hn[0]); MFMA(ah1, bhnv, hn[1]);
      }
      #pragma unroll
      for (int mi = 0; mi < 2; ++mi)
        #pragma unroll
        for (int e = 0; e < 4; ++e) {
          float r  = fast_sigmoid(gr[mi][e] + hr[mi][e]);
          float zz = fast_sigmoid(gz[mi][e] + hz[mi][e]);
          float nn = fast_tanh(gn[mi][e] + r * hn[mi][e]);
          float ho = h1m[ji][mi][e];
          float hv = nn + zz * (ho - nn);
          h1m[ji][mi][e] = hv;
          h1w[(mi * 16 + q * 4 + e) * 136 + J * 16 + c] = f2bf(hv);
        }
    }
    __syncthreads();
    axc[0] = axn[0]; axc[1] = axn[1];
  }

  #pragma unroll
  for (int ji = 0; ji < 2; ++ji) {
    const int J = 2 * w + ji;
    #pragma unroll
    for (int mi = 0; mi < 2; ++mi)
      #pragma unroll
      for (int e = 0; e < 4; ++e) {
        int seq = seq0 + mi * 16 + q * 4 + e;
        hout[(size_t)seq * 128 + J * 16 + c] = h1m[ji][mi][e];
      }
  }
}

// ---------------------------------------------------------------------------
// Kernel 3: mean over routes + candidate head + fc1/fc2/fc3 (unchanged)
// ---------------------------------------------------------------------------
__global__ __launch_bounds__(192) void final_kernel(
    const float* __restrict__ hout, const float* __restrict__ cands,
    const float* __restrict__ cw, const float* __restrict__ cb,
    const float* __restrict__ f1w, const float* __restrict__ f1b,
    const float* __restrict__ f2w, const float* __restrict__ f2b,
    const float* __restrict__ f3w, const float* __restrict__ f3b,
    float* __restrict__ out) {
  __shared__ float hc[192];
  __shared__ float v1[128];
  __shared__ float v2[128];
  __shared__ float red[128];
  const int b = blockIdx.x, tid = threadIdx.x;
  if (tid < 128) {
    float s = 0.f;
    const float* hp = hout + (size_t)(b * 48) * 128 + tid;
    #pragma unroll 4
    for (int r = 0; r < 48; ++r) s += hp[r * 128];
    hc[tid] = s * (1.0f / 48.0f);
  } else {
    int j = tid - 128;
    float s = cb[j];
    const float* cp = cands + b * 72;
    #pragma unroll 8
    for (int k = 0; k < 72; ++k) s += cp[k] * cw[k * 64 + j];
    hc[128 + j] = s;
  }
  __syncthreads();
  if (tid < 128) {
    float s = f1b[tid];
    for (int k = 0; k < 192; ++k) s += hc[k] * f1w[k * 128 + tid];
    v1[tid] = fast_tanh(s);
  }
  __syncthreads();
  if (tid < 128) {
    float s = f2b[tid];
    for (int k = 0; k < 128; ++k) s += v1[k] * f2w[k * 128 + tid];
    v2[tid] = fast_tanh(s);
  }
  __syncthreads();
  if (tid < 128) red[tid] = v2[tid] * f3w[tid];
  __syncthreads();
  if (tid < 64) {
    float s = red[tid] + red[tid + 64];
    s += __shfl_down(s, 32);
    s += __shfl_down(s, 16);
    s += __shfl_down(s, 8);
    s += __shfl_down(s, 4);
    s += __shfl_down(s, 2);
    s += __shfl_down(s, 1);
    if (tid == 0) out[b] = s + f3b[0];
  }
}

// ---------------------------------------------------------------------------
extern "C" void kernel_launch(void* const* d_in, const int* in_sizes, int n_in,
                              void* d_out, int out_size, void* d_ws, size_t ws_size,
                              hipStream_t stream) {
  const float* cand  = (const float*)d_in[0];
  const float* cust  = (const float*)d_in[1];
  const float* w1    = (const float*)d_in[2];
  const float* b1    = (const float*)d_in[3];
  const float* w2    = (const float*)d_in[4];
  const float* b2    = (const float*)d_in[5];
  const float* wih0  = (const float*)d_in[6];
  const float* whh0  = (const float*)d_in[7];
  const float* bih0  = (const float*)d_in[8];
  const float* bhh0  = (const float*)d_in[9];
  const float* wih1  = (const float*)d_in[10];
  const float* whh1  = (const float*)d_in[11];
  const float* bih1  = (const float*)d_in[12];
  const float* bhh1  = (const float*)d_in[13];
  const float* cw    = (const float*)d_in[14];
  const float* cb    = (const float*)d_in[15];
  const float* f1w   = (const float*)d_in[16];
  const float* f1b   = (const float*)d_in[17];
  const float* f2w   = (const float*)d_in[18];
  const float* f2b   = (const float*)d_in[19];
  const float* f3w   = (const float*)d_in[20];
  const float* f3b   = (const float*)d_in[21];

  uint16_t* wsp = (uint16_t*)d_ws;
  uint16_t* x2p = wsp + X2_EL;
  float* outp = (float*)d_out;

  pack_weights<<<(PK_END + 255) / 256, 256, 0, stream>>>(w1, w2, wih0, whh0, wih1, whh1, wsp);
  mlp_kernel<<<(NSEQ * TSTEPS) / 128, 256, 0, stream>>>(cust, b1, b2, wsp, x2p);

  if (ws_size >= WS_NEED_NEW) {
    uint16_t* h0g = wsp + H0_EL;
    float* hout = (float*)((char*)d_ws + HOUT_NEW_BYTE);
    gru_split<<<NSEQ / 32, 256, 0, stream>>>(wsp, x2p, h0g, bih0, bhh0, bih1, bhh1, hout);
    final_kernel<<<512, 192, 0, stream>>>(hout, cand, cw, cb, f1w, f1b, f2w, f2b, f3w, f3b, outp);
  } else {
    float* hout = (float*)((char*)d_ws + HOUT_OLD_BYTE);
    gru_fused<<<NSEQ / 32, 256, 0, stream>>>(wsp, x2p, bih0, bhh0, bih1, bhh1, hout);
    final_kernel<<<512, 192, 0, stream>>>(hout, cand, cw, cb, f1w, f1b, f2w, f2b, f3w, f3b, outp);
  }
}

// Round 3
// 499.932 us; speedup vs baseline: 1.2627x; 1.2627x over previous
//
#include <hip/hip_runtime.h>
#include <stdint.h>

// ---------------------------------------------------------------------------
// MLP_Model: candidates head + per-route Customer MLP + 2-layer GRU + FC head
// R3: FUSED GRU (h stays in LDS, no global round-trip — R2's 938MB HBM mistake
// reverted) + ALL weights register-resident (R2's one validated idea).
// gru_res: 256 thr = 4 waves, wave owns J-tiles {2w,2w+1}, 32 seqs/block,
// __launch_bounds__(256,1): ~440 VGPR/wave, 1 block/CU, grid=768 (3 rounds).
// Per-step memory = LDS only + one tiny x2 prefetch.
// ws layout: [0,344064) packed bf16 weights; [344064,38092800) x2 bf16;
// [38092800,...) h1 final fp32 (~50.7 MB total, same as R1).
// ---------------------------------------------------------------------------

#define NSEQ   24576   // 512 * 48
#define TSTEPS 24

typedef __attribute__((ext_vector_type(8))) short bf16x8;
typedef __attribute__((ext_vector_type(4))) float floatx4;

// packed-weight element offsets (uint16 units)
#define PK_W1    0
#define PK_W2    8192
#define PK_WIH0  12288
#define PK_WHH0  24576
#define PK_WIH1  73728
#define PK_WHH1  122880
#define PK_END   172032
#define X2_EL    172032                 // x2: [t][seq][32] bf16
#define HOUT_BYTE 38092800              // h1 final: [seq][128] fp32

#define MFMA(a,b,c) c = __builtin_amdgcn_mfma_f32_16x16x32_bf16(a, b, c, 0, 0, 0)

__device__ __forceinline__ uint16_t f2bf(float f) {
  uint32_t u = __float_as_uint(f);
  u += 0x7FFFu + ((u >> 16) & 1u);           // RNE
  return (uint16_t)(u >> 16);
}
__device__ __forceinline__ float fast_sigmoid(float x) {
  float e = __builtin_amdgcn_exp2f(-1.4426950408889634f * x);
  return __builtin_amdgcn_rcpf(1.0f + e);
}
__device__ __forceinline__ float fast_tanh(float x) {
  float e = __builtin_amdgcn_exp2f(-2.8853900817779268f * x);
  return 2.0f * __builtin_amdgcn_rcpf(1.0f + e) - 1.0f;
}
__device__ __forceinline__ bf16x8 ldf(const uint16_t* p) {
  return *(const bf16x8*)p;
}

// ---------------------------------------------------------------------------
// Kernel 0: pack all weights to bf16 B-fragment layout. (unchanged)
// frag = nt*KB + kb ; elem(lane,j) = W[kb*32 + (lane>>4)*8 + j][nt*16 + (lane&15)]
// ---------------------------------------------------------------------------
__global__ __launch_bounds__(256) void pack_weights(
    const float* __restrict__ w1, const float* __restrict__ w2,
    const float* __restrict__ wih0, const float* __restrict__ whh0,
    const float* __restrict__ wih1, const float* __restrict__ whh1,
    uint16_t* __restrict__ ws) {
  int idx = blockIdx.x * 256 + threadIdx.x;
  if (idx >= PK_END) return;
  const float* W; int N, KB, Kreal, base;
  if      (idx <  8192) { W = w1;   N = 128; KB = 2; Kreal = 36;  base = 0; }
  else if (idx < 12288) { W = w2;   N = 32;  KB = 4; Kreal = 128; base = 8192; }
  else if (idx < 24576) { W = wih0; N = 384; KB = 1; Kreal = 32;  base = 12288; }
  else if (idx < 73728) { W = whh0; N = 384; KB = 4; Kreal = 128; base = 24576; }
  else if (idx < 122880){ W = wih1; N = 384; KB = 4; Kreal = 128; base = 73728; }
  else                  { W = whh1; N = 384; KB = 4; Kreal = 128; base = 122880; }
  int li = idx - base;
  int frag = li >> 9;
  int e = li & 511;
  int lane = e >> 3, j = e & 7;
  int kb = frag % KB, nt = frag / KB;
  int k = kb * 32 + (lane >> 4) * 8 + j;
  int n = nt * 16 + (lane & 15);
  float v = (k < Kreal) ? W[k * N + n] : 0.0f;
  ws[base + li] = f2bf(v);
}

// ---------------------------------------------------------------------------
// Kernel 1: Customer MLP (unchanged from R1)
// ---------------------------------------------------------------------------
__global__ __launch_bounds__(256) void mlp_kernel(
    const float* __restrict__ customers, const float* __restrict__ b1,
    const float* __restrict__ b2, const uint16_t* __restrict__ wpk,
    uint16_t* __restrict__ x2out) {
  __shared__ uint16_t sA[128 * 136];
  const int r0 = blockIdx.x * 128;
  const int t  = r0 / NSEQ;
  const int s0 = r0 % NSEQ;
  const int tid = threadIdx.x;
  const int w = tid >> 6, l = tid & 63, q = l >> 4, c = l & 15;
  const int lo8 = l * 8;

  float b1r[8], b2r[2];
  #pragma unroll
  for (int nt = 0; nt < 8; ++nt) b1r[nt] = b1[nt * 16 + c];
  b2r[0] = b2[c]; b2r[1] = b2[16 + c];

  floatx4 acc[2][8];
  #pragma unroll
  for (int mi = 0; mi < 2; ++mi)
    #pragma unroll
    for (int nt = 0; nt < 8; ++nt) acc[mi][nt] = (floatx4){0.f, 0.f, 0.f, 0.f};

  #pragma unroll
  for (int mi = 0; mi < 2; ++mi) {
    const int mt = 2 * w + mi;
    const int seq = s0 + mt * 16 + c;
    const float* xp = customers + (size_t)seq * 864 + t * 36;
    floatx4 u0 = *(const floatx4*)(xp + q * 8);
    floatx4 u1 = *(const floatx4*)(xp + q * 8 + 4);
    bf16x8 a0;
    a0[0] = (short)f2bf(u0[0]); a0[1] = (short)f2bf(u0[1]);
    a0[2] = (short)f2bf(u0[2]); a0[3] = (short)f2bf(u0[3]);
    a0[4] = (short)f2bf(u1[0]); a0[5] = (short)f2bf(u1[1]);
    a0[6] = (short)f2bf(u1[2]); a0[7] = (short)f2bf(u1[3]);
    bf16x8 a1x = (bf16x8){0,0,0,0,0,0,0,0};
    if (q == 0) {
      floatx4 u2 = *(const floatx4*)(xp + 32);
      a1x[0] = (short)f2bf(u2[0]); a1x[1] = (short)f2bf(u2[1]);
      a1x[2] = (short)f2bf(u2[2]); a1x[3] = (short)f2bf(u2[3]);
    }
    #pragma unroll
    for (int nt = 0; nt < 8; ++nt) {
      bf16x8 bv0 = ldf(wpk + PK_W1 + (nt * 2 + 0) * 512 + lo8);
      bf16x8 bv1 = ldf(wpk + PK_W1 + (nt * 2 + 1) * 512 + lo8);
      MFMA(a0,  bv0, acc[mi][nt]);
      MFMA(a1x, bv1, acc[mi][nt]);
    }
  }
  #pragma unroll
  for (int mi = 0; mi < 2; ++mi) {
    const int mt = 2 * w + mi;
    #pragma unroll
    for (int nt = 0; nt < 8; ++nt)
      #pragma unroll
      for (int e = 0; e < 4; ++e) {
        float v = fast_tanh(acc[mi][nt][e] + b1r[nt]);
        sA[(mt * 16 + q * 4 + e) * 136 + nt * 16 + c] = f2bf(v);
      }
  }
  __syncthreads();

  floatx4 acc2[2][2];
  #pragma unroll
  for (int mi = 0; mi < 2; ++mi)
    #pragma unroll
    for (int nt = 0; nt < 2; ++nt) acc2[mi][nt] = (floatx4){0.f, 0.f, 0.f, 0.f};

  #pragma unroll
  for (int kb = 0; kb < 4; ++kb) {
    bf16x8 av0 = ldf(&sA[((2 * w + 0) * 16 + c) * 136 + kb * 32 + q * 8]);
    bf16x8 av1 = ldf(&sA[((2 * w + 1) * 16 + c) * 136 + kb * 32 + q * 8]);
    #pragma unroll
    for (int nt = 0; nt < 2; ++nt) {
      bf16x8 bv = ldf(wpk + PK_W2 + (nt * 4 + kb) * 512 + lo8);
      MFMA(av0, bv, acc2[0][nt]);
      MFMA(av1, bv, acc2[1][nt]);
    }
  }
  #pragma unroll
  for (int mi = 0; mi < 2; ++mi) {
    const int mt = 2 * w + mi;
    #pragma unroll
    for (int nt = 0; nt < 2; ++nt)
      #pragma unroll
      for (int e = 0; e < 4; ++e) {
        float v = fast_tanh(acc2[mi][nt][e] + b2r[nt]);
        int m = mt * 16 + q * 4 + e;
        x2out[(size_t)(r0 + m) * 32 + nt * 16 + c] = f2bf(v);
      }
  }
}

// ---------------------------------------------------------------------------
// Kernel 2 (R3): fused 2-layer GRU, ALL weights register-resident.
// 256 thr = 4 waves, wave owns J-tiles {2w, 2w+1}, 32 seqs/block, grid 768.
// __launch_bounds__(256,1): up to 512 VGPR/wave; ~440 used, 1 block/CU.
// Per-step traffic: LDS only (h double-buffered) + 2 small x2 loads.
// ---------------------------------------------------------------------------
__global__ __launch_bounds__(256, 1) void gru_res(
    const uint16_t* __restrict__ wpk, const uint16_t* __restrict__ x2,
    const float* __restrict__ bih0, const float* __restrict__ bhh0,
    const float* __restrict__ bih1, const float* __restrict__ bhh1,
    float* __restrict__ hout) {
  __shared__ uint16_t hl[2][2][32 * 136];   // [layer][buf][row*136]
  const int seq0 = blockIdx.x * 32;
  const int tid = threadIdx.x;
  const int w = tid >> 6, l = tid & 63, q = l >> 4, c = l & 15;
  const int lo8 = l * 8;

  { uint32_t* z = (uint32_t*)hl;
    for (int i = tid; i < 8704; i += 256) z[i] = 0u; }

  // ---- load ALL weight fragments for this wave's two J-tiles into VGPRs ----
  bf16x8 wi0[2][3], wh0[2][3][4], wi1[2][3][4], wh1[2][3][4];
  float bR0[2], bZ0[2], bN0[2], bH0[2];
  float bR1[2], bZ1[2], bN1[2], bH1[2];
  #pragma unroll
  for (int ji = 0; ji < 2; ++ji) {
    const int J = 2 * w + ji;
    #pragma unroll
    for (int g = 0; g < 3; ++g) {
      wi0[ji][g] = ldf(wpk + PK_WIH0 + (g * 8 + J) * 512 + lo8);
      #pragma unroll
      for (int kb = 0; kb < 4; ++kb) {
        wh0[ji][g][kb] = ldf(wpk + PK_WHH0 + ((g * 8 + J) * 4 + kb) * 512 + lo8);
        wi1[ji][g][kb] = ldf(wpk + PK_WIH1 + ((g * 8 + J) * 4 + kb) * 512 + lo8);
        wh1[ji][g][kb] = ldf(wpk + PK_WHH1 + ((g * 8 + J) * 4 + kb) * 512 + lo8);
      }
    }
    const int col = J * 16 + c;
    bR0[ji] = bih0[col]       + bhh0[col];
    bZ0[ji] = bih0[128 + col] + bhh0[128 + col];
    bN0[ji] = bih0[256 + col];
    bH0[ji] = bhh0[256 + col];
    bR1[ji] = bih1[col]       + bhh1[col];
    bZ1[ji] = bih1[128 + col] + bhh1[128 + col];
    bN1[ji] = bih1[256 + col];
    bH1[ji] = bhh1[256 + col];
  }

  floatx4 h0m[2][2], h1m[2][2];
  #pragma unroll
  for (int ji = 0; ji < 2; ++ji)
    #pragma unroll
    for (int mi = 0; mi < 2; ++mi) {
      h0m[ji][mi] = (floatx4){0.f, 0.f, 0.f, 0.f};
      h1m[ji][mi] = (floatx4){0.f, 0.f, 0.f, 0.f};
    }

  bf16x8 axc[2];
  axc[0] = ldf(x2 + (size_t)(seq0 + c) * 32 + q * 8);
  axc[1] = ldf(x2 + (size_t)(seq0 + 16 + c) * 32 + q * 8);
  __syncthreads();

  #pragma unroll 1
  for (int t = 0; t < TSTEPS; ++t) {
    const int cur = t & 1, prv = cur ^ 1;
    const int tn = (t < TSTEPS - 1) ? t + 1 : t;
    bf16x8 axn0 = ldf(x2 + ((size_t)tn * NSEQ + seq0 + c) * 32 + q * 8);
    bf16x8 axn1 = ldf(x2 + ((size_t)tn * NSEQ + seq0 + 16 + c) * 32 + q * 8);

    uint16_t* h0w = hl[0][cur]; const uint16_t* h0r = hl[0][prv];
    uint16_t* h1w = hl[1][cur]; const uint16_t* h1r = hl[1][prv];

    // ---------------- layer 0 ----------------
    {
      floatx4 aR[2][2], aZ[2][2], aN[2][2], aH[2][2];
      #pragma unroll
      for (int ji = 0; ji < 2; ++ji)
        #pragma unroll
        for (int mi = 0; mi < 2; ++mi) {
          aR[ji][mi] = (floatx4){bR0[ji], bR0[ji], bR0[ji], bR0[ji]};
          aZ[ji][mi] = (floatx4){bZ0[ji], bZ0[ji], bZ0[ji], bZ0[ji]};
          aN[ji][mi] = (floatx4){bN0[ji], bN0[ji], bN0[ji], bN0[ji]};
          aH[ji][mi] = (floatx4){bH0[ji], bH0[ji], bH0[ji], bH0[ji]};
        }
      #pragma unroll
      for (int kb = 0; kb < 4; ++kb) {
        bf16x8 a0 = ldf(h0r + (c)      * 136 + kb * 32 + q * 8);
        bf16x8 a1 = ldf(h0r + (16 + c) * 136 + kb * 32 + q * 8);
        #pragma unroll
        for (int ji = 0; ji < 2; ++ji) {
          MFMA(a0, wh0[ji][0][kb], aR[ji][0]); MFMA(a1, wh0[ji][0][kb], aR[ji][1]);
          MFMA(a0, wh0[ji][1][kb], aZ[ji][0]); MFMA(a1, wh0[ji][1][kb], aZ[ji][1]);
          MFMA(a0, wh0[ji][2][kb], aH[ji][0]); MFMA(a1, wh0[ji][2][kb], aH[ji][1]);
        }
      }
      #pragma unroll
      for (int ji = 0; ji < 2; ++ji) {
        MFMA(axc[0], wi0[ji][0], aR[ji][0]); MFMA(axc[1], wi0[ji][0], aR[ji][1]);
        MFMA(axc[0], wi0[ji][1], aZ[ji][0]); MFMA(axc[1], wi0[ji][1], aZ[ji][1]);
        MFMA(axc[0], wi0[ji][2], aN[ji][0]); MFMA(axc[1], wi0[ji][2], aN[ji][1]);
      }
      #pragma unroll
      for (int ji = 0; ji < 2; ++ji) {
        const int J = 2 * w + ji;
        #pragma unroll
        for (int mi = 0; mi < 2; ++mi)
          #pragma unroll
          for (int e = 0; e < 4; ++e) {
            float r  = fast_sigmoid(aR[ji][mi][e]);
            float zz = fast_sigmoid(aZ[ji][mi][e]);
            float nn = fast_tanh(aN[ji][mi][e] + r * aH[ji][mi][e]);
            float hv = nn + zz * (h0m[ji][mi][e] - nn);
            h0m[ji][mi][e] = hv;
            h0w[(mi * 16 + q * 4 + e) * 136 + J * 16 + c] = f2bf(hv);
          }
      }
    }
    __syncthreads();

    // ---------------- layer 1 ----------------
    {
      floatx4 aR[2][2], aZ[2][2], aN[2][2], aH[2][2];
      #pragma unroll
      for (int ji = 0; ji < 2; ++ji)
        #pragma unroll
        for (int mi = 0; mi < 2; ++mi) {
          aR[ji][mi] = (floatx4){bR1[ji], bR1[ji], bR1[ji], bR1[ji]};
          aZ[ji][mi] = (floatx4){bZ1[ji], bZ1[ji], bZ1[ji], bZ1[ji]};
          aN[ji][mi] = (floatx4){bN1[ji], bN1[ji], bN1[ji], bN1[ji]};
          aH[ji][mi] = (floatx4){bH1[ji], bH1[ji], bH1[ji], bH1[ji]};
        }
      #pragma unroll
      for (int kb = 0; kb < 4; ++kb) {
        bf16x8 ai0 = ldf(h0w + (c)      * 136 + kb * 32 + q * 8);
        bf16x8 ai1 = ldf(h0w + (16 + c) * 136 + kb * 32 + q * 8);
        bf16x8 ah0 = ldf(h1r + (c)      * 136 + kb * 32 + q * 8);
        bf16x8 ah1 = ldf(h1r + (16 + c) * 136 + kb * 32 + q * 8);
        #pragma unroll
        for (int ji = 0; ji < 2; ++ji) {
          MFMA(ai0, wi1[ji][0][kb], aR[ji][0]); MFMA(ai1, wi1[ji][0][kb], aR[ji][1]);
          MFMA(ai0, wi1[ji][1][kb], aZ[ji][0]); MFMA(ai1, wi1[ji][1][kb], aZ[ji][1]);
          MFMA(ai0, wi1[ji][2][kb], aN[ji][0]); MFMA(ai1, wi1[ji][2][kb], aN[ji][1]);
          MFMA(ah0, wh1[ji][0][kb], aR[ji][0]); MFMA(ah1, wh1[ji][0][kb], aR[ji][1]);
          MFMA(ah0, wh1[ji][1][kb], aZ[ji][0]); MFMA(ah1, wh1[ji][1][kb], aZ[ji][1]);
          MFMA(ah0, wh1[ji][2][kb], aH[ji][0]); MFMA(ah1, wh1[ji][2][kb], aH[ji][1]);
        }
      }
      #pragma unroll
      for (int ji = 0; ji < 2; ++ji) {
        const int J = 2 * w + ji;
        #pragma unroll
        for (int mi = 0; mi < 2; ++mi)
          #pragma unroll
          for (int e = 0; e < 4; ++e) {
            float r  = fast_sigmoid(aR[ji][mi][e]);
            float zz = fast_sigmoid(aZ[ji][mi][e]);
            float nn = fast_tanh(aN[ji][mi][e] + r * aH[ji][mi][e]);
            float hv = nn + zz * (h1m[ji][mi][e] - nn);
            h1m[ji][mi][e] = hv;
            h1w[(mi * 16 + q * 4 + e) * 136 + J * 16 + c] = f2bf(hv);
          }
      }
    }
    __syncthreads();
    axc[0] = axn0; axc[1] = axn1;
  }

  #pragma unroll
  for (int ji = 0; ji < 2; ++ji) {
    const int J = 2 * w + ji;
    #pragma unroll
    for (int mi = 0; mi < 2; ++mi)
      #pragma unroll
      for (int e = 0; e < 4; ++e) {
        int seq = seq0 + mi * 16 + q * 4 + e;
        hout[(size_t)seq * 128 + J * 16 + c] = h1m[ji][mi][e];
      }
  }
}

// ---------------------------------------------------------------------------
// Kernel 3: mean over routes + candidate head + fc1/fc2/fc3 (unchanged)
// ---------------------------------------------------------------------------
__global__ __launch_bounds__(192) void final_kernel(
    const float* __restrict__ hout, const float* __restrict__ cands,
    const float* __restrict__ cw, const float* __restrict__ cb,
    const float* __restrict__ f1w, const float* __restrict__ f1b,
    const float* __restrict__ f2w, const float* __restrict__ f2b,
    const float* __restrict__ f3w, const float* __restrict__ f3b,
    float* __restrict__ out) {
  __shared__ float hc[192];
  __shared__ float v1[128];
  __shared__ float v2[128];
  __shared__ float red[128];
  const int b = blockIdx.x, tid = threadIdx.x;
  if (tid < 128) {
    float s = 0.f;
    const float* hp = hout + (size_t)(b * 48) * 128 + tid;
    #pragma unroll 4
    for (int r = 0; r < 48; ++r) s += hp[r * 128];
    hc[tid] = s * (1.0f / 48.0f);
  } else {
    int j = tid - 128;
    float s = cb[j];
    const float* cp = cands + b * 72;
    #pragma unroll 8
    for (int k = 0; k < 72; ++k) s += cp[k] * cw[k * 64 + j];
    hc[128 + j] = s;
  }
  __syncthreads();
  if (tid < 128) {
    float s = f1b[tid];
    for (int k = 0; k < 192; ++k) s += hc[k] * f1w[k * 128 + tid];
    v1[tid] = fast_tanh(s);
  }
  __syncthreads();
  if (tid < 128) {
    float s = f2b[tid];
    for (int k = 0; k < 128; ++k) s += v1[k] * f2w[k * 128 + tid];
    v2[tid] = fast_tanh(s);
  }
  __syncthreads();
  if (tid < 128) red[tid] = v2[tid] * f3w[tid];
  __syncthreads();
  if (tid < 64) {
    float s = red[tid] + red[tid + 64];
    s += __shfl_down(s, 32);
    s += __shfl_down(s, 16);
    s += __shfl_down(s, 8);
    s += __shfl_down(s, 4);
    s += __shfl_down(s, 2);
    s += __shfl_down(s, 1);
    if (tid == 0) out[b] = s + f3b[0];
  }
}

// ---------------------------------------------------------------------------
extern "C" void kernel_launch(void* const* d_in, const int* in_sizes, int n_in,
                              void* d_out, int out_size, void* d_ws, size_t ws_size,
                              hipStream_t stream) {
  const float* cand  = (const float*)d_in[0];
  const float* cust  = (const float*)d_in[1];
  const float* w1    = (const float*)d_in[2];
  const float* b1    = (const float*)d_in[3];
  const float* w2    = (const float*)d_in[4];
  const float* b2    = (const float*)d_in[5];
  const float* wih0  = (const float*)d_in[6];
  const float* whh0  = (const float*)d_in[7];
  const float* bih0  = (const float*)d_in[8];
  const float* bhh0  = (const float*)d_in[9];
  const float* wih1  = (const float*)d_in[10];
  const float* whh1  = (const float*)d_in[11];
  const float* bih1  = (const float*)d_in[12];
  const float* bhh1  = (const float*)d_in[13];
  const float* cw    = (const float*)d_in[14];
  const float* cb    = (const float*)d_in[15];
  const float* f1w   = (const float*)d_in[16];
  const float* f1b   = (const float*)d_in[17];
  const float* f2w   = (const float*)d_in[18];
  const float* f2b   = (const float*)d_in[19];
  const float* f3w   = (const float*)d_in[20];
  const float* f3b   = (const float*)d_in[21];

  uint16_t* wsp = (uint16_t*)d_ws;
  uint16_t* x2p = wsp + X2_EL;
  float* hout = (float*)((char*)d_ws + HOUT_BYTE);
  float* outp = (float*)d_out;

  pack_weights<<<(PK_END + 255) / 256, 256, 0, stream>>>(w1, w2, wih0, whh0, wih1, whh1, wsp);
  mlp_kernel<<<(NSEQ * TSTEPS) / 128, 256, 0, stream>>>(cust, b1, b2, wsp, x2p);
  gru_res<<<NSEQ / 32, 256, 0, stream>>>(wsp, x2p, bih0, bhh0, bih1, bhh1, hout);
  final_kernel<<<512, 192, 0, stream>>>(hout, cand, cw, cb, f1w, f1b, f2w, f2b, f3w, f3b, outp);
}

// Round 4
// 428.937 us; speedup vs baseline: 1.4716x; 1.1655x over previous
//
#include <hip/hip_runtime.h>
#include <stdint.h>

// ---------------------------------------------------------------------------
// MLP_Model: candidates head + per-route Customer MLP + 2-layer GRU + FC head
// R4: gru_res now 512 threads = 8 waves, EACH WAVE OWNS ONE J-TILE.
// Weight fragments per wave: 39 (156 VGPR) -> total ~235 VGPR, fits the
// 256-VGPR/wave budget at __launch_bounds__(512,2) with NO spills (R3's
// 2-J-tiles/wave demanded ~440 and silently spilled ~180 regs -> 314us).
// Everything else (pack/mlp/final) unchanged from R3.
// ws layout: [0,344064) packed bf16 weights; [344064,38092800) x2 bf16;
// [38092800,...) h1 final fp32 (~50.7 MB total).
// ---------------------------------------------------------------------------

#define NSEQ   24576   // 512 * 48
#define TSTEPS 24

typedef __attribute__((ext_vector_type(8))) short bf16x8;
typedef __attribute__((ext_vector_type(4))) float floatx4;

// packed-weight element offsets (uint16 units)
#define PK_W1    0
#define PK_W2    8192
#define PK_WIH0  12288
#define PK_WHH0  24576
#define PK_WIH1  73728
#define PK_WHH1  122880
#define PK_END   172032
#define X2_EL    172032                 // x2: [t][seq][32] bf16
#define HOUT_BYTE 38092800              // h1 final: [seq][128] fp32

#define MFMA(a,b,c) c = __builtin_amdgcn_mfma_f32_16x16x32_bf16(a, b, c, 0, 0, 0)

__device__ __forceinline__ uint16_t f2bf(float f) {
  uint32_t u = __float_as_uint(f);
  u += 0x7FFFu + ((u >> 16) & 1u);           // RNE
  return (uint16_t)(u >> 16);
}
__device__ __forceinline__ float fast_sigmoid(float x) {
  float e = __builtin_amdgcn_exp2f(-1.4426950408889634f * x);
  return __builtin_amdgcn_rcpf(1.0f + e);
}
__device__ __forceinline__ float fast_tanh(float x) {
  float e = __builtin_amdgcn_exp2f(-2.8853900817779268f * x);
  return 2.0f * __builtin_amdgcn_rcpf(1.0f + e) - 1.0f;
}
__device__ __forceinline__ bf16x8 ldf(const uint16_t* p) {
  return *(const bf16x8*)p;
}

// ---------------------------------------------------------------------------
// Kernel 0: pack all weights to bf16 B-fragment layout. (unchanged)
// ---------------------------------------------------------------------------
__global__ __launch_bounds__(256) void pack_weights(
    const float* __restrict__ w1, const float* __restrict__ w2,
    const float* __restrict__ wih0, const float* __restrict__ whh0,
    const float* __restrict__ wih1, const float* __restrict__ whh1,
    uint16_t* __restrict__ ws) {
  int idx = blockIdx.x * 256 + threadIdx.x;
  if (idx >= PK_END) return;
  const float* W; int N, KB, Kreal, base;
  if      (idx <  8192) { W = w1;   N = 128; KB = 2; Kreal = 36;  base = 0; }
  else if (idx < 12288) { W = w2;   N = 32;  KB = 4; Kreal = 128; base = 8192; }
  else if (idx < 24576) { W = wih0; N = 384; KB = 1; Kreal = 32;  base = 12288; }
  else if (idx < 73728) { W = whh0; N = 384; KB = 4; Kreal = 128; base = 24576; }
  else if (idx < 122880){ W = wih1; N = 384; KB = 4; Kreal = 128; base = 73728; }
  else                  { W = whh1; N = 384; KB = 4; Kreal = 128; base = 122880; }
  int li = idx - base;
  int frag = li >> 9;
  int e = li & 511;
  int lane = e >> 3, j = e & 7;
  int kb = frag % KB, nt = frag / KB;
  int k = kb * 32 + (lane >> 4) * 8 + j;
  int n = nt * 16 + (lane & 15);
  float v = (k < Kreal) ? W[k * N + n] : 0.0f;
  ws[base + li] = f2bf(v);
}

// ---------------------------------------------------------------------------
// Kernel 1: Customer MLP (unchanged from R1)
// ---------------------------------------------------------------------------
__global__ __launch_bounds__(256) void mlp_kernel(
    const float* __restrict__ customers, const float* __restrict__ b1,
    const float* __restrict__ b2, const uint16_t* __restrict__ wpk,
    uint16_t* __restrict__ x2out) {
  __shared__ uint16_t sA[128 * 136];
  const int r0 = blockIdx.x * 128;
  const int t  = r0 / NSEQ;
  const int s0 = r0 % NSEQ;
  const int tid = threadIdx.x;
  const int w = tid >> 6, l = tid & 63, q = l >> 4, c = l & 15;
  const int lo8 = l * 8;

  float b1r[8], b2r[2];
  #pragma unroll
  for (int nt = 0; nt < 8; ++nt) b1r[nt] = b1[nt * 16 + c];
  b2r[0] = b2[c]; b2r[1] = b2[16 + c];

  floatx4 acc[2][8];
  #pragma unroll
  for (int mi = 0; mi < 2; ++mi)
    #pragma unroll
    for (int nt = 0; nt < 8; ++nt) acc[mi][nt] = (floatx4){0.f, 0.f, 0.f, 0.f};

  #pragma unroll
  for (int mi = 0; mi < 2; ++mi) {
    const int mt = 2 * w + mi;
    const int seq = s0 + mt * 16 + c;
    const float* xp = customers + (size_t)seq * 864 + t * 36;
    floatx4 u0 = *(const floatx4*)(xp + q * 8);
    floatx4 u1 = *(const floatx4*)(xp + q * 8 + 4);
    bf16x8 a0;
    a0[0] = (short)f2bf(u0[0]); a0[1] = (short)f2bf(u0[1]);
    a0[2] = (short)f2bf(u0[2]); a0[3] = (short)f2bf(u0[3]);
    a0[4] = (short)f2bf(u1[0]); a0[5] = (short)f2bf(u1[1]);
    a0[6] = (short)f2bf(u1[2]); a0[7] = (short)f2bf(u1[3]);
    bf16x8 a1x = (bf16x8){0,0,0,0,0,0,0,0};
    if (q == 0) {
      floatx4 u2 = *(const floatx4*)(xp + 32);
      a1x[0] = (short)f2bf(u2[0]); a1x[1] = (short)f2bf(u2[1]);
      a1x[2] = (short)f2bf(u2[2]); a1x[3] = (short)f2bf(u2[3]);
    }
    #pragma unroll
    for (int nt = 0; nt < 8; ++nt) {
      bf16x8 bv0 = ldf(wpk + PK_W1 + (nt * 2 + 0) * 512 + lo8);
      bf16x8 bv1 = ldf(wpk + PK_W1 + (nt * 2 + 1) * 512 + lo8);
      MFMA(a0,  bv0, acc[mi][nt]);
      MFMA(a1x, bv1, acc[mi][nt]);
    }
  }
  #pragma unroll
  for (int mi = 0; mi < 2; ++mi) {
    const int mt = 2 * w + mi;
    #pragma unroll
    for (int nt = 0; nt < 8; ++nt)
      #pragma unroll
      for (int e = 0; e < 4; ++e) {
        float v = fast_tanh(acc[mi][nt][e] + b1r[nt]);
        sA[(mt * 16 + q * 4 + e) * 136 + nt * 16 + c] = f2bf(v);
      }
  }
  __syncthreads();

  floatx4 acc2[2][2];
  #pragma unroll
  for (int mi = 0; mi < 2; ++mi)
    #pragma unroll
    for (int nt = 0; nt < 2; ++nt) acc2[mi][nt] = (floatx4){0.f, 0.f, 0.f, 0.f};

  #pragma unroll
  for (int kb = 0; kb < 4; ++kb) {
    bf16x8 av0 = ldf(&sA[((2 * w + 0) * 16 + c) * 136 + kb * 32 + q * 8]);
    bf16x8 av1 = ldf(&sA[((2 * w + 1) * 16 + c) * 136 + kb * 32 + q * 8]);
    #pragma unroll
    for (int nt = 0; nt < 2; ++nt) {
      bf16x8 bv = ldf(wpk + PK_W2 + (nt * 4 + kb) * 512 + lo8);
      MFMA(av0, bv, acc2[0][nt]);
      MFMA(av1, bv, acc2[1][nt]);
    }
  }
  #pragma unroll
  for (int mi = 0; mi < 2; ++mi) {
    const int mt = 2 * w + mi;
    #pragma unroll
    for (int nt = 0; nt < 2; ++nt)
      #pragma unroll
      for (int e = 0; e < 4; ++e) {
        float v = fast_tanh(acc2[mi][nt][e] + b2r[nt]);
        int m = mt * 16 + q * 4 + e;
        x2out[(size_t)(r0 + m) * 32 + nt * 16 + c] = f2bf(v);
      }
  }
}

// ---------------------------------------------------------------------------
// Kernel 2 (R4): fused 2-layer GRU, weights register-resident, 8 waves,
// wave w owns J-tile w. 32 seqs/block, grid 768, 1 block/CU (2 waves/SIMD).
// ---------------------------------------------------------------------------
__global__ __launch_bounds__(512, 2) void gru_res(
    const uint16_t* __restrict__ wpk, const uint16_t* __restrict__ x2,
    const float* __restrict__ bih0, const float* __restrict__ bhh0,
    const float* __restrict__ bih1, const float* __restrict__ bhh1,
    float* __restrict__ hout) {
  __shared__ uint16_t hl[2][2][32 * 136];   // [layer][buf][row*136]
  const int seq0 = blockIdx.x * 32;
  const int tid = threadIdx.x;
  const int J = tid >> 6, l = tid & 63, q = l >> 4, c = l & 15;
  const int lo8 = l * 8;

  { uint32_t* z = (uint32_t*)hl;
    for (int i = tid; i < 8704; i += 512) z[i] = 0u; }

  // ---- load this wave's J-tile weight fragments into VGPRs (39 frags) ----
  bf16x8 wi0[3], wh0[3][4], wi1[3][4], wh1[3][4];
  #pragma unroll
  for (int g = 0; g < 3; ++g) {
    wi0[g] = ldf(wpk + PK_WIH0 + (g * 8 + J) * 512 + lo8);
    #pragma unroll
    for (int kb = 0; kb < 4; ++kb) {
      wh0[g][kb] = ldf(wpk + PK_WHH0 + ((g * 8 + J) * 4 + kb) * 512 + lo8);
      wi1[g][kb] = ldf(wpk + PK_WIH1 + ((g * 8 + J) * 4 + kb) * 512 + lo8);
      wh1[g][kb] = ldf(wpk + PK_WHH1 + ((g * 8 + J) * 4 + kb) * 512 + lo8);
    }
  }
  const int col = J * 16 + c;
  const float bR0 = bih0[col]       + bhh0[col];
  const float bZ0 = bih0[128 + col] + bhh0[128 + col];
  const float bN0 = bih0[256 + col];
  const float bH0 = bhh0[256 + col];
  const float bR1 = bih1[col]       + bhh1[col];
  const float bZ1 = bih1[128 + col] + bhh1[128 + col];
  const float bN1 = bih1[256 + col];
  const float bH1 = bhh1[256 + col];

  floatx4 h0m[2], h1m[2];
  h0m[0] = (floatx4){0.f, 0.f, 0.f, 0.f}; h0m[1] = (floatx4){0.f, 0.f, 0.f, 0.f};
  h1m[0] = (floatx4){0.f, 0.f, 0.f, 0.f}; h1m[1] = (floatx4){0.f, 0.f, 0.f, 0.f};

  bf16x8 axc[2];
  axc[0] = ldf(x2 + (size_t)(seq0 + c) * 32 + q * 8);
  axc[1] = ldf(x2 + (size_t)(seq0 + 16 + c) * 32 + q * 8);
  __syncthreads();

  #pragma unroll 1
  for (int t = 0; t < TSTEPS; ++t) {
    const int cur = t & 1, prv = cur ^ 1;
    const int tn = (t < TSTEPS - 1) ? t + 1 : t;
    bf16x8 axn0 = ldf(x2 + ((size_t)tn * NSEQ + seq0 + c) * 32 + q * 8);
    bf16x8 axn1 = ldf(x2 + ((size_t)tn * NSEQ + seq0 + 16 + c) * 32 + q * 8);

    uint16_t* h0w = hl[0][cur]; const uint16_t* h0r = hl[0][prv];
    uint16_t* h1w = hl[1][cur]; const uint16_t* h1r = hl[1][prv];

    // ---------------- layer 0 ----------------
    {
      floatx4 aR[2], aZ[2], aN[2], aH[2];
      #pragma unroll
      for (int mi = 0; mi < 2; ++mi) {
        aR[mi] = (floatx4){bR0, bR0, bR0, bR0};
        aZ[mi] = (floatx4){bZ0, bZ0, bZ0, bZ0};
        aN[mi] = (floatx4){bN0, bN0, bN0, bN0};
        aH[mi] = (floatx4){bH0, bH0, bH0, bH0};
      }
      #pragma unroll
      for (int kb = 0; kb < 4; ++kb) {
        bf16x8 a0 = ldf(h0r + (c)      * 136 + kb * 32 + q * 8);
        bf16x8 a1 = ldf(h0r + (16 + c) * 136 + kb * 32 + q * 8);
        MFMA(a0, wh0[0][kb], aR[0]); MFMA(a1, wh0[0][kb], aR[1]);
        MFMA(a0, wh0[1][kb], aZ[0]); MFMA(a1, wh0[1][kb], aZ[1]);
        MFMA(a0, wh0[2][kb], aH[0]); MFMA(a1, wh0[2][kb], aH[1]);
      }
      MFMA(axc[0], wi0[0], aR[0]); MFMA(axc[1], wi0[0], aR[1]);
      MFMA(axc[0], wi0[1], aZ[0]); MFMA(axc[1], wi0[1], aZ[1]);
      MFMA(axc[0], wi0[2], aN[0]); MFMA(axc[1], wi0[2], aN[1]);
      #pragma unroll
      for (int mi = 0; mi < 2; ++mi)
        #pragma unroll
        for (int e = 0; e < 4; ++e) {
          float r  = fast_sigmoid(aR[mi][e]);
          float zz = fast_sigmoid(aZ[mi][e]);
          float nn = fast_tanh(aN[mi][e] + r * aH[mi][e]);
          float hv = nn + zz * (h0m[mi][e] - nn);
          h0m[mi][e] = hv;
          h0w[(mi * 16 + q * 4 + e) * 136 + J * 16 + c] = f2bf(hv);
        }
    }
    __syncthreads();

    // ---------------- layer 1 ----------------
    {
      floatx4 aR[2], aZ[2], aN[2], aH[2];
      #pragma unroll
      for (int mi = 0; mi < 2; ++mi) {
        aR[mi] = (floatx4){bR1, bR1, bR1, bR1};
        aZ[mi] = (floatx4){bZ1, bZ1, bZ1, bZ1};
        aN[mi] = (floatx4){bN1, bN1, bN1, bN1};
        aH[mi] = (floatx4){bH1, bH1, bH1, bH1};
      }
      #pragma unroll
      for (int kb = 0; kb < 4; ++kb) {
        bf16x8 ai0 = ldf(h0w + (c)      * 136 + kb * 32 + q * 8);
        bf16x8 ai1 = ldf(h0w + (16 + c) * 136 + kb * 32 + q * 8);
        bf16x8 ah0 = ldf(h1r + (c)      * 136 + kb * 32 + q * 8);
        bf16x8 ah1 = ldf(h1r + (16 + c) * 136 + kb * 32 + q * 8);
        MFMA(ai0, wi1[0][kb], aR[0]); MFMA(ai1, wi1[0][kb], aR[1]);
        MFMA(ai0, wi1[1][kb], aZ[0]); MFMA(ai1, wi1[1][kb], aZ[1]);
        MFMA(ai0, wi1[2][kb], aN[0]); MFMA(ai1, wi1[2][kb], aN[1]);
        MFMA(ah0, wh1[0][kb], aR[0]); MFMA(ah1, wh1[0][kb], aR[1]);
        MFMA(ah0, wh1[1][kb], aZ[0]); MFMA(ah1, wh1[1][kb], aZ[1]);
        MFMA(ah0, wh1[2][kb], aH[0]); MFMA(ah1, wh1[2][kb], aH[1]);
      }
      #pragma unroll
      for (int mi = 0; mi < 2; ++mi)
        #pragma unroll
        for (int e = 0; e < 4; ++e) {
          float r  = fast_sigmoid(aR[mi][e]);
          float zz = fast_sigmoid(aZ[mi][e]);
          float nn = fast_tanh(aN[mi][e] + r * aH[mi][e]);
          float hv = nn + zz * (h1m[mi][e] - nn);
          h1m[mi][e] = hv;
          h1w[(mi * 16 + q * 4 + e) * 136 + J * 16 + c] = f2bf(hv);
        }
    }
    __syncthreads();
    axc[0] = axn0; axc[1] = axn1;
  }

  #pragma unroll
  for (int mi = 0; mi < 2; ++mi)
    #pragma unroll
    for (int e = 0; e < 4; ++e) {
      int seq = seq0 + mi * 16 + q * 4 + e;
      hout[(size_t)seq * 128 + J * 16 + c] = h1m[mi][e];
    }
}

// ---------------------------------------------------------------------------
// Kernel 3: mean over routes + candidate head + fc1/fc2/fc3 (unchanged)
// ---------------------------------------------------------------------------
__global__ __launch_bounds__(192) void final_kernel(
    const float* __restrict__ hout, const float* __restrict__ cands,
    const float* __restrict__ cw, const float* __restrict__ cb,
    const float* __restrict__ f1w, const float* __restrict__ f1b,
    const float* __restrict__ f2w, const float* __restrict__ f2b,
    const float* __restrict__ f3w, const float* __restrict__ f3b,
    float* __restrict__ out) {
  __shared__ float hc[192];
  __shared__ float v1[128];
  __shared__ float v2[128];
  __shared__ float red[128];
  const int b = blockIdx.x, tid = threadIdx.x;
  if (tid < 128) {
    float s = 0.f;
    const float* hp = hout + (size_t)(b * 48) * 128 + tid;
    #pragma unroll 4
    for (int r = 0; r < 48; ++r) s += hp[r * 128];
    hc[tid] = s * (1.0f / 48.0f);
  } else {
    int j = tid - 128;
    float s = cb[j];
    const float* cp = cands + b * 72;
    #pragma unroll 8
    for (int k = 0; k < 72; ++k) s += cp[k] * cw[k * 64 + j];
    hc[128 + j] = s;
  }
  __syncthreads();
  if (tid < 128) {
    float s = f1b[tid];
    for (int k = 0; k < 192; ++k) s += hc[k] * f1w[k * 128 + tid];
    v1[tid] = fast_tanh(s);
  }
  __syncthreads();
  if (tid < 128) {
    float s = f2b[tid];
    for (int k = 0; k < 128; ++k) s += v1[k] * f2w[k * 128 + tid];
    v2[tid] = fast_tanh(s);
  }
  __syncthreads();
  if (tid < 128) red[tid] = v2[tid] * f3w[tid];
  __syncthreads();
  if (tid < 64) {
    float s = red[tid] + red[tid + 64];
    s += __shfl_down(s, 32);
    s += __shfl_down(s, 16);
    s += __shfl_down(s, 8);
    s += __shfl_down(s, 4);
    s += __shfl_down(s, 2);
    s += __shfl_down(s, 1);
    if (tid == 0) out[b] = s + f3b[0];
  }
}

// ---------------------------------------------------------------------------
extern "C" void kernel_launch(void* const* d_in, const int* in_sizes, int n_in,
                              void* d_out, int out_size, void* d_ws, size_t ws_size,
                              hipStream_t stream) {
  const float* cand  = (const float*)d_in[0];
  const float* cust  = (const float*)d_in[1];
  const float* w1    = (const float*)d_in[2];
  const float* b1    = (const float*)d_in[3];
  const float* w2    = (const float*)d_in[4];
  const float* b2    = (const float*)d_in[5];
  const float* wih0  = (const float*)d_in[6];
  const float* whh0  = (const float*)d_in[7];
  const float* bih0  = (const float*)d_in[8];
  const float* bhh0  = (const float*)d_in[9];
  const float* wih1  = (const float*)d_in[10];
  const float* whh1  = (const float*)d_in[11];
  const float* bih1  = (const float*)d_in[12];
  const float* bhh1  = (const float*)d_in[13];
  const float* cw    = (const float*)d_in[14];
  const float* cb    = (const float*)d_in[15];
  const float* f1w   = (const float*)d_in[16];
  const float* f1b   = (const float*)d_in[17];
  const float* f2w   = (const float*)d_in[18];
  const float* f2b   = (const float*)d_in[19];
  const float* f3w   = (const float*)d_in[20];
  const float* f3b   = (const float*)d_in[21];

  uint16_t* wsp = (uint16_t*)d_ws;
  uint16_t* x2p = wsp + X2_EL;
  float* hout = (float*)((char*)d_ws + HOUT_BYTE);
  float* outp = (float*)d_out;

  pack_weights<<<(PK_END + 255) / 256, 256, 0, stream>>>(w1, w2, wih0, whh0, wih1, whh1, wsp);
  mlp_kernel<<<(NSEQ * TSTEPS) / 128, 256, 0, stream>>>(cust, b1, b2, wsp, x2p);
  gru_res<<<NSEQ / 32, 512, 0, stream>>>(wsp, x2p, bih0, bhh0, bih1, bhh1, hout);
  final_kernel<<<512, 192, 0, stream>>>(hout, cand, cw, cb, f1w, f1b, f2w, f2b, f3w, f3b, outp);
}